// Round 3
// baseline (409.387 us; speedup 1.0000x reference)
//
#include <hip/hip_runtime.h>

// Shapes fixed by the reference: N=2, C=32, H=W=64, O=32, K=3, stride=1, pad=1.
// out[n][o][oh][ow] = relu( sum_k patch[n,l,k] * filt[n,l,k,o] ),  l = oh*W+ow
// filters slice per (n,l): [288,32] row-major contiguous = 9216 floats (36 KB).
// filters total = 302 MB read-once => memory-bound; floor ~48 us at 6.3 TB/s.
//
// Two kernels:
//  1) im2col: materialize all feature patches [8192 x 288] into d_ws (9.4 MB)
//     so the stream kernel's prologue is coalesced (no scattered gather/divmod).
//  2) stream: ONE WAVE PER LOCATION; 2 coalesced float4 patch loads -> LDS;
//     36 x float4 coalesced filter loads (plain, so Infinity-Cache hits from
//     the harness's restore copy are allowed); shuffle-reduce; ReLU; store.
//     __launch_bounds__(256,4) caps VGPRs at 128 -> 16 waves/CU for stream
//     concurrency.

#define C_   32
#define H_   64
#define W_   64
#define O_   32
#define CKK_ 288
#define L_   (H_ * W_)

typedef float vf4 __attribute__((ext_vector_type(4)));

__global__ __launch_bounds__(256) void im2col_kernel(
    const float* __restrict__ features,
    float* __restrict__ patches,        // [N*L, 288]
    int total)                          // N*L*288
{
    const int idx = blockIdx.x * 256 + threadIdx.x;
    if (idx >= total) return;
    const int loc = idx / CKK_;
    const int k   = idx % CKK_;
    const int n   = loc >> 12;          // / L_
    const int l   = loc & (L_ - 1);
    const int oh  = l >> 6;
    const int ow  = l & (W_ - 1);
    const int c   = k / 9;
    const int r   = k % 9;
    const int ih  = oh + (r / 3) - 1;
    const int iw  = ow + (r % 3) - 1;
    float v = 0.0f;
    if ((unsigned)ih < (unsigned)H_ && (unsigned)iw < (unsigned)W_)
        v = features[((n * C_ + c) * H_ + ih) * W_ + iw];
    patches[idx] = v;
}

__global__ __launch_bounds__(256, 4) void convfilt_kernel(
    const float* __restrict__ patches,  // [N*L, 288]
    const float* __restrict__ filters,  // [N*L, 288, 32]
    float* __restrict__ out)            // [N, 32, H, W]
{
    const int wave = threadIdx.x >> 6;
    const int lane = threadIdx.x & 63;
    const int loc  = blockIdx.x * 4 + wave;     // n*L + l, one wave per location
    const int n    = loc >> 12;
    const int l    = loc & (L_ - 1);

    __shared__ float sf[4][CKK_];
    float* __restrict__ s = sf[wave];           // wave-private segment

    // ---- prologue: 72 float4 = the 288-float patch, coalesced ----
    const vf4* __restrict__ pp = (const vf4*)(patches + (size_t)loc * CKK_);
    vf4 pa = pp[lane];
    vf4 pb;
    if (lane < 8) pb = pp[64 + lane];
    ((vf4*)s)[lane] = pa;
    if (lane < 8) ((vf4*)s)[64 + lane] = pb;
    __syncthreads();

    // ---- stream the [288,32] filter slice: 36 x 64-lane float4, coalesced ----
    const vf4* __restrict__ fp =
        (const vf4*)(filters + (size_t)loc * (CKK_ * O_));
    const int g = lane >> 3;                    // k-cluster: k = 8j + g

    float a0 = 0.f, a1 = 0.f, a2 = 0.f, a3 = 0.f;
    #pragma unroll
    for (int j = 0; j < 36; ++j) {
        const vf4   f  = fp[j * 64 + lane];
        const float fv = s[j * 8 + g];          // broadcast per 8-lane cluster
        a0 = fmaf(f.x, fv, a0);
        a1 = fmaf(f.y, fv, a1);
        a2 = fmaf(f.z, fv, a2);
        a3 = fmaf(f.w, fv, a3);
    }

    // ---- reduce over the 8 clusters (lanes m, m+8, ..., m+56 share o-group) ----
    #pragma unroll
    for (int st = 8; st < 64; st <<= 1) {
        a0 += __shfl_down(a0, st);
        a1 += __shfl_down(a1, st);
        a2 += __shfl_down(a2, st);
        a3 += __shfl_down(a3, st);
    }

    // ---- ReLU + store: lane m (<8) owns o = 4m..4m+3 ----
    if (lane < 8) {
        float* op = out + ((size_t)n * O_ + lane * 4) * L_ + l;
        op[0 * L_] = fmaxf(a0, 0.f);
        op[1 * L_] = fmaxf(a1, 0.f);
        op[2 * L_] = fmaxf(a2, 0.f);
        op[3 * L_] = fmaxf(a3, 0.f);
    }
}

extern "C" void kernel_launch(void* const* d_in, const int* in_sizes, int n_in,
                              void* d_out, int out_size, void* d_ws, size_t ws_size,
                              hipStream_t stream)
{
    const float* features = (const float*)d_in[0];   // [N, C, H, W]
    const float* filters  = (const float*)d_in[1];   // [N, L, Ckk, O]
    float* out            = (float*)d_out;           // [N, O, H, W]
    float* patches        = (float*)d_ws;            // [N*L, 288] = 9.4 MB

    const int N     = in_sizes[0] / (C_ * H_ * W_);  // = 2
    const int nloc  = N * L_;                        // 8192 locations
    const int pelem = nloc * CKK_;                   // 2,359,296 patch elements

    im2col_kernel<<<(pelem + 255) / 256, 256, 0, stream>>>(features, patches, pelem);
    convfilt_kernel<<<nloc / 4, 256, 0, stream>>>(patches, filters, out);
}

// Round 4
// 400.581 us; speedup vs baseline: 1.0220x; 1.0220x over previous
//
#include <hip/hip_runtime.h>

// Shapes fixed by the reference: N=2, C=32, H=W=64, O=32, K=3, stride=1, pad=1.
// out[n][o][oh][ow] = relu( sum_k patch[k] * filt[n, l, k, o] ),  l = oh*W+ow
// filters slice per (n,l): [288,32] row-major contiguous = 9216 floats (36 KB).
// filters = 302 MB read-once => memory-bound. Harness restores filters via D2D
// copy right before the kernel, so much of it is L3-resident: use PLAIN loads
// (no nontemporal) to allow Infinity-Cache hits.
//
// ONE WAVE PER LOCATION, waves fully independent, NO BARRIER:
//  - each wave gathers its 288-float feature patch into a wave-private LDS
//    segment (per-wave lgkmcnt ordering suffices; no __syncthreads, so filter
//    loads can be hoisted/overlapped by the scheduler)
//  - 36 x float4 coalesced loads stream the filter slice
//    (lane covers float4 index j*64+lane -> k = 8j + lane/8, o = 4*(lane%8)..+3)
//  - 3-step shuffle reduction over the 8 k-clusters, ReLU, store.

#define C_   32
#define H_   64
#define W_   64
#define O_   32
#define CKK_ 288
#define L_   (H_ * W_)

typedef float vf4 __attribute__((ext_vector_type(4)));

__global__ __launch_bounds__(256) void convfilt_kernel(
    const float* __restrict__ features,
    const float* __restrict__ filters,
    float* __restrict__ out)
{
    const int wave = threadIdx.x >> 6;
    const int lane = threadIdx.x & 63;
    const int loc  = blockIdx.x * 4 + wave;     // n*L + l, one wave per location

    const int n  = loc >> 12;                   // / 4096
    const int l  = loc & (L_ - 1);
    const int oh = l >> 6;
    const int ow = l & (W_ - 1);

    __shared__ float sf[4][CKK_];
    float* __restrict__ s = sf[wave];           // wave-private segment (no barrier)

    // ---- gather the 288-element feature patch (zero pad) into LDS ----
    #pragma unroll
    for (int q = 0; q < 5; ++q) {
        const int e = q * 64 + lane;            // q=4: only lanes <32 active
        if (e < CKK_) {
            const int c  = e / 9;
            const int r  = e % 9;
            const int ih = oh + (r / 3) - 1;
            const int iw = ow + (r % 3) - 1;
            float v = 0.0f;
            if ((unsigned)ih < (unsigned)H_ && (unsigned)iw < (unsigned)W_)
                v = features[((n * C_ + c) * H_ + ih) * W_ + iw];
            s[e] = v;
        }
    }
    // no __syncthreads(): each wave only touches its own LDS segment; the
    // compiler's lgkmcnt tracking orders the ds_write -> ds_read within a wave.

    // ---- stream the [288,32] filter slice: 36 x 64-lane float4, coalesced ----
    const vf4* __restrict__ fp =
        (const vf4*)(filters + (size_t)loc * (CKK_ * O_));
    const int g = lane >> 3;                    // k-cluster: k = 8j + g

    float a0 = 0.f, a1 = 0.f, a2 = 0.f, a3 = 0.f;
    #pragma unroll
    for (int j = 0; j < 36; ++j) {
        const vf4   f  = fp[j * 64 + lane];     // plain load: allow L3 hits
        const float fv = s[j * 8 + g];          // broadcast per 8-lane cluster
        a0 = fmaf(f.x, fv, a0);
        a1 = fmaf(f.y, fv, a1);
        a2 = fmaf(f.z, fv, a2);
        a3 = fmaf(f.w, fv, a3);
    }

    // ---- reduce over the 8 clusters (lanes m, m+8, ..., m+56 share o-group) ----
    #pragma unroll
    for (int st = 8; st < 64; st <<= 1) {
        a0 += __shfl_down(a0, st);
        a1 += __shfl_down(a1, st);
        a2 += __shfl_down(a2, st);
        a3 += __shfl_down(a3, st);
    }

    // ---- ReLU + store: lane m (<8) owns o = 4m..4m+3 ----
    if (lane < 8) {
        float* op = out + ((size_t)n * O_ + lane * 4) * L_ + l;
        op[0 * L_] = fmaxf(a0, 0.f);
        op[1 * L_] = fmaxf(a1, 0.f);
        op[2 * L_] = fmaxf(a2, 0.f);
        op[3 * L_] = fmaxf(a3, 0.f);
    }
}

extern "C" void kernel_launch(void* const* d_in, const int* in_sizes, int n_in,
                              void* d_out, int out_size, void* d_ws, size_t ws_size,
                              hipStream_t stream)
{
    const float* features = (const float*)d_in[0];   // [N, C, H, W]
    const float* filters  = (const float*)d_in[1];   // [N, L, Ckk, O]
    float* out            = (float*)d_out;           // [N, O, H, W]

    const int N     = in_sizes[0] / (C_ * H_ * W_);  // = 2
    const int total = N * L_;                        // 8192 locations
    const int grid  = total / 4;                     // 4 waves (locations) per block

    convfilt_kernel<<<grid, 256, 0, stream>>>(features, filters, out);
}

// Round 5
// 372.775 us; speedup vs baseline: 1.0982x; 1.0746x over previous
//
#include <hip/hip_runtime.h>

// Shapes fixed by the reference: N=2, C=32, H=W=64, O=32, K=3, stride=1, pad=1.
// out[n][o][oh][ow] = relu( sum_k patch[k] * filt[n, l, k, o] ),  l = oh*W+ow
// filters slice per (n,l): [288,32] row-major contiguous = 9216 floats (36 KB).
// filters = 302 MB read-once => memory-bound; kernel floor ~48 us at 6.3 TB/s.
//
// Measured config facts: nontemporal filter loads + __syncthreads (R2) = best
// (375 us total); plain loads / no barrier regressed (+25 us) — the harness's
// 1.18 GB ws re-poison flushes L3 between the filter restore and our kernel,
// so L3 never hits and nt streaming is strictly better.
//
// This round: TWO ADJACENT LOCATIONS PER WAVE (l even, l+1) to amortize the
// per-wave prologue (scattered feature gather + barrier drain) and epilogue
// (shuffle reduce + stores) over 72 KB of stream instead of 36 KB, and to
// fuse the epilogue stores into float2 (adjacent l are contiguous in out).

#define C_   32
#define H_   64
#define W_   64
#define O_   32
#define CKK_ 288
#define L_   (H_ * W_)

typedef float vf4 __attribute__((ext_vector_type(4)));
typedef float vf2 __attribute__((ext_vector_type(2)));

__global__ __launch_bounds__(256) void convfilt_kernel(
    const float* __restrict__ features,
    const float* __restrict__ filters,
    float* __restrict__ out)
{
    const int wave = threadIdx.x >> 6;
    const int lane = threadIdx.x & 63;
    const int loc0 = blockIdx.x * 8 + wave * 2;   // even location; pair = loc0, loc0+1
    const int n    = loc0 >> 12;                  // / 4096
    const int l0   = loc0 & (L_ - 1);
    const int oh   = l0 >> 6;
    const int ow   = l0 & (W_ - 1);               // even => ow+1 stays in-row

    __shared__ float sf[4][2][CKK_];
    float* __restrict__ s0 = sf[wave][0];         // wave-private segments
    float* __restrict__ s1 = sf[wave][1];

    // ---- gather both 288-element feature patches (zero pad) into LDS ----
    #pragma unroll
    for (int q = 0; q < 5; ++q) {
        const int e = q * 64 + lane;              // q=4: only lanes <32 active
        if (e < CKK_) {
            const int c  = e / 9;
            const int r  = e % 9;
            const int ih = oh + (r / 3) - 1;
            const int iw = ow + (r % 3) - 1;
            float v0 = 0.0f, v1 = 0.0f;
            if ((unsigned)ih < (unsigned)H_) {
                const float* fb = features + ((n * C_ + c) * H_ + ih) * W_;
                if ((unsigned)iw       < (unsigned)W_) v0 = fb[iw];
                if ((unsigned)(iw + 1) < (unsigned)W_) v1 = fb[iw + 1];
            }
            s0[e] = v0;
            s1[e] = v1;
        }
    }
    __syncthreads();

    // ---- stream both [288,32] filter slices: 72 x 64-lane float4, nt ----
    const vf4* __restrict__ fp0 =
        (const vf4*)(filters + (size_t)loc0 * (CKK_ * O_));
    const vf4* __restrict__ fp1 = fp0 + (CKK_ * O_ / 4);
    const int g = lane >> 3;                      // k-cluster: k = 8j + g

    float a0 = 0.f, a1 = 0.f, a2 = 0.f, a3 = 0.f;   // loc0 acc
    float b0 = 0.f, b1 = 0.f, b2 = 0.f, b3 = 0.f;   // loc1 acc
    #pragma unroll
    for (int j = 0; j < 36; ++j) {
        const vf4 f0 = __builtin_nontemporal_load(fp0 + j * 64 + lane);
        const vf4 f1 = __builtin_nontemporal_load(fp1 + j * 64 + lane);
        const float u0 = s0[j * 8 + g];
        const float u1 = s1[j * 8 + g];
        a0 = fmaf(f0.x, u0, a0);  a1 = fmaf(f0.y, u0, a1);
        a2 = fmaf(f0.z, u0, a2);  a3 = fmaf(f0.w, u0, a3);
        b0 = fmaf(f1.x, u1, b0);  b1 = fmaf(f1.y, u1, b1);
        b2 = fmaf(f1.z, u1, b2);  b3 = fmaf(f1.w, u1, b3);
    }

    // ---- reduce over the 8 clusters (lanes m, m+8, ..., m+56 share o-group) ----
    #pragma unroll
    for (int st = 8; st < 64; st <<= 1) {
        a0 += __shfl_down(a0, st);  a1 += __shfl_down(a1, st);
        a2 += __shfl_down(a2, st);  a3 += __shfl_down(a3, st);
        b0 += __shfl_down(b0, st);  b1 += __shfl_down(b1, st);
        b2 += __shfl_down(b2, st);  b3 += __shfl_down(b3, st);
    }

    // ---- ReLU + store: lane m (<8) owns o = 4m..4m+3; l0,l0+1 contiguous ----
    if (lane < 8) {
        float* op = out + ((size_t)n * O_ + lane * 4) * L_ + l0;
        vf2 r0 = { fmaxf(a0, 0.f), fmaxf(b0, 0.f) };
        vf2 r1 = { fmaxf(a1, 0.f), fmaxf(b1, 0.f) };
        vf2 r2 = { fmaxf(a2, 0.f), fmaxf(b2, 0.f) };
        vf2 r3 = { fmaxf(a3, 0.f), fmaxf(b3, 0.f) };
        *(vf2*)(op + 0 * L_) = r0;
        *(vf2*)(op + 1 * L_) = r1;
        *(vf2*)(op + 2 * L_) = r2;
        *(vf2*)(op + 3 * L_) = r3;
    }
}

extern "C" void kernel_launch(void* const* d_in, const int* in_sizes, int n_in,
                              void* d_out, int out_size, void* d_ws, size_t ws_size,
                              hipStream_t stream)
{
    const float* features = (const float*)d_in[0];   // [N, C, H, W]
    const float* filters  = (const float*)d_in[1];   // [N, L, Ckk, O]
    float* out            = (float*)d_out;           // [N, O, H, W]

    const int N     = in_sizes[0] / (C_ * H_ * W_);  // = 2
    const int total = N * L_;                        // 8192 locations
    const int grid  = total / 8;                     // 4 waves x 2 locations per block

    convfilt_kernel<<<grid, 256, 0, stream>>>(features, filters, out);
}